// Round 13
// baseline (101.278 us; speedup 1.0000x reference)
//
#include <hip/hip_runtime.h>

// LTC via Chebyshev-GEMM, v8: register-A + v7's B-pipeline.
//   out[bt,u] = sA/(1+fs); fs,sA = [BT x 448]*[448 x 512] fp16 GEMM.
// R12 diagnosis: v3/v7 are LDS-PORT-bound (~1900 of 2230 cyc/K-step/CU is
// ds traffic; LDS is per-CU, MFMA per-SIMD -> 5x oversubscribed). v8 deletes
// ALL A-side LDS ops: the MFMA A-fragment is lane-local, so each lane carries
// T_k state for its own (row,d) set in f16x8 regs (tc/tp/x2, advanced by
// v_pk_fma_f16) -- proven correct in v4. B keeps v7's per-K-step dbuf glds
// staging (swizzled source cols) with ONE barrier per K-step.
// No launch_bounds min-waves: ~200 VGPR -> 2 waves/SIMD, no spill (v6 lesson:
// the (256,2) bound forced a 128-VGPR cap and 1GB of scratch traffic).

typedef _Float16 f16;
typedef _Float16 f16x8 __attribute__((ext_vector_type(8)));
typedef float f32x4 __attribute__((ext_vector_type(4)));

#if __has_builtin(__builtin_amdgcn_rcpf)
#define RCP(x) __builtin_amdgcn_rcpf(x)
#else
#define RCP(x) (1.0f / (x))
#endif
#if __has_builtin(__builtin_amdgcn_exp2f)
#define EXP2(x) __builtin_amdgcn_exp2f(x)
#else
#define EXP2(x) exp2f(x)
#endif

namespace {
constexpr int D  = 64, U = 256, TT = 1024, BB = 128;
constexpr int BT = BB * TT;              // 131072 GEMM rows
constexpr int NK = 8;                    // degree 7
constexpr int KD = (NK - 1) * 64;        // K = 448
constexpr int ND = 2 * U;                // N = 512
constexpr float SCALE = 6.5f;
constexpr size_t WT_BYTES = (size_t)ND * KD * sizeof(f16);
constexpr float L2E = 1.4426950408889634f;
}

// ---------------- kernel 0: per-(u,d) Chebyshev coefficients ----------------
__global__ __launch_bounds__(64) void wgen(
    const float* __restrict__ Aw, const float* __restrict__ sg,
    const float* __restrict__ mu, f16* __restrict__ Wt, float* __restrict__ bias)
{
    const int u = blockIdx.x, d = threadIdx.x;
    const int id = u * 64 + d;
    const float s = sg[id], m = mu[id], a = Aw[id];
    float g[NK], th[NK];
    float q0 = 0.f;
#pragma unroll
    for (int j = 0; j < NK; ++j) {
        th[j] = 3.14159265358979323846f * (float)(2 * j + 1) / (float)(2 * NK);
        float xj = SCALE * cosf(th[j]);
        g[j] = 1.f / (1.f + expf(-s * (xj - m)));
        q0 += g[j];
    }
    q0 *= (1.f / NK);
#pragma unroll
    for (int k = 1; k < NK; ++k) {
        float qk = 0.f;
#pragma unroll
        for (int j = 0; j < NK; ++j) qk += g[j] * cosf((float)k * th[j]);
        qk *= (2.f / NK);
        Wt[(size_t)(2 * u)     * KD + (k - 1) * 64 + d] = (f16)qk;
        Wt[(size_t)(2 * u + 1) * KD + (k - 1) * 64 + d] = (f16)(a * qk);
    }
    float b0 = q0, b1 = a * q0;
#pragma unroll
    for (int off = 1; off < 64; off <<= 1) {
        b0 += __shfl_xor(b0, off);
        b1 += __shfl_xor(b1, off);
    }
    if (d == 0) { bias[2 * u] = 1.f + b0; bias[2 * u + 1] = b1; }
}

// ---------------- fused GEMM, register-A, B-dbuf ----------------
#define GLDS16(g, l) __builtin_amdgcn_global_load_lds( \
    (const __attribute__((address_space(1))) void*)(g), \
    (__attribute__((address_space(3))) void*)(l), 16, 0, 0)

__global__ __launch_bounds__(256) void gemm_ltc(
    const float* __restrict__ Xg, const f16* __restrict__ Wt,
    const float* __restrict__ bias, float* __restrict__ outp)
{
    const int tid = threadIdx.x;
    // XCD swizzle (v3/v7-identical: FETCH 18MB)
    const int cpx  = gridDim.x >> 3;
    const int swz  = (blockIdx.x & 7) * cpx + (blockIdx.x >> 3);
    const int nblk = swz & 3;            // 128 N-cols each
    const int mblk = swz >> 2;           // 128 rows each
    const int lane = tid & 63, w = tid >> 6;
    const int wr = w >> 1, wc = w & 1;   // 2x2 waves, 64x64 tile each
    const int fr = lane & 15, fq = lane >> 4;
    const int rxr = fr & 7;

    __shared__ f16 Bsh[2][128 * 64];     // 16 KB x2 (dbuf); NO A in LDS

    // ---- B staging (src-col XOR permute, linear glds dest) — v7-identical
    const int srow8 = tid >> 3, slot = tid & 7;
    const int scol  = ((slot ^ (srow8 & 7)) * 8);
    const f16* Bb = Wt + (size_t)(nblk * 128 + srow8) * KD + scol;
#define STAGEB(buf, ks)                                                     \
    {                                                                       \
        _Pragma("unroll")                                                   \
        for (int i = 0; i < 4; ++i)                                         \
            GLDS16(Bb + (size_t)i * 32 * KD + (ks) * 64,                    \
                   &Bsh[buf][i * 2048 + tid * 8]);                          \
    }

    STAGEB(0, 0);   // in flight under X load + convert

    // ---- per-lane Chebyshev state == the MFMA A-fragments (v4-proven):
    // rows mblk*128 + wr*64 + m*16 + fr, d = kk*32 + fq*8 + j
    f16x8 tc[4][2], tp[4][2], x2[4][2];
    {
        const float inv = 1.0f / SCALE;
        const float* xb = Xg + (size_t)(mblk * 128 + wr * 64 + fr) * 64 + fq * 8;
#pragma unroll
        for (int m = 0; m < 4; ++m)
#pragma unroll
            for (int kk = 0; kk < 2; ++kk) {
                const float* p = xb + (size_t)m * 16 * 64 + kk * 32;
                f32x4 lo = *(const f32x4*)p;
                f32x4 hi = *(const f32x4*)(p + 4);
                f16x8 t;
#pragma unroll
                for (int j = 0; j < 4; ++j) {
                    t[j]     = (f16)(lo[j] * inv);
                    t[4 + j] = (f16)(hi[j] * inv);
                }
                tc[m][kk] = t;                    // T_1
                x2[m][kk] = t + t;                // 2 x^
                tp[m][kk] = f16x8{(f16)1.f,(f16)1.f,(f16)1.f,(f16)1.f,
                                  (f16)1.f,(f16)1.f,(f16)1.f,(f16)1.f};  // T_0
            }
    }

    f32x4 acc[4][4];
#pragma unroll
    for (int m = 0; m < 4; ++m)
#pragma unroll
        for (int n = 0; n < 4; ++n) acc[m][n] = f32x4{0.f, 0.f, 0.f, 0.f};

    asm volatile("s_waitcnt vmcnt(0)");
    __syncthreads();                     // B0 ready

    // ---- B read offsets (v7-identical swizzle)
    const int brow = (wc * 64 + fr) * 128;   // bytes: row = wc*64 + n*16 + fr via +n*2048
    int colu[2];
#pragma unroll
    for (int kk = 0; kk < 2; ++kk) colu[kk] = (((kk * 4 + fq) ^ rxr) * 16);

#pragma unroll
    for (int ks = 0; ks < KD / 64; ++ks) {
        const int c = ks & 1;
        if (ks < KD / 64 - 1) STAGEB(c ^ 1, ks + 1);   // issue first (hide L2 lat)
        const char* Bc = (const char*)Bsh[c];
#pragma unroll
        for (int kk = 0; kk < 2; ++kk) {
            f16x8 bf[4];
#pragma unroll
            for (int n = 0; n < 4; ++n)
                bf[n] = *(const f16x8*)(Bc + brow + n * 2048 + colu[kk]);
#pragma unroll
            for (int m = 0; m < 4; ++m)
#pragma unroll
                for (int n = 0; n < 4; ++n)
                    acc[m][n] = __builtin_amdgcn_mfma_f32_16x16x32_f16(
                        tc[m][kk], bf[n], acc[m][n], 0, 0, 0);
        }
        if (ks < KD / 64 - 1) {
            // T-advance in registers (4 v_pk_fma_f16 per fragment)
#pragma unroll
            for (int m = 0; m < 4; ++m)
#pragma unroll
                for (int kk = 0; kk < 2; ++kk) {
                    f16x8 tn = x2[m][kk] * tc[m][kk] - tp[m][kk];
                    tp[m][kk] = tc[m][kk];
                    tc[m][kk] = tn;
                }
        }
        __syncthreads();   // B(ks+1) arrived (vmcnt drained by barrier)
    }

    // ---- epilogue (v7-identical): pair (2u,2u+1) via shfl_xor(1)
    const int ncb = nblk * 128 + wc * 64;
    float bia[4];
#pragma unroll
    for (int n = 0; n < 4; ++n) bia[n] = bias[ncb + n * 16 + fr];
    const int growb = mblk * 128 + wr * 64;
    const bool evenl = !(fr & 1);
#pragma unroll
    for (int m = 0; m < 4; ++m) {
        const int r0 = growb + m * 16 + fq * 4;
#pragma unroll
        for (int n = 0; n < 4; ++n) {
            const int ucol = (ncb + n * 16 + fr) >> 1;
            f32x4 v = acc[m][n];
#pragma unroll
            for (int e = 0; e < 4; ++e) {
                float full = v[e] + bia[n];
                float oth  = __shfl_xor(full, 1);
                if (evenl) outp[(size_t)(r0 + e) * U + ucol] = oth * RCP(full);
            }
        }
    }
}

// ---------------- fallback (proven R3 kernel) for tiny ws ----------------
__global__ __launch_bounds__(256) void ltc_fused2_kernel(
    const float* __restrict__ inp, const float* __restrict__ A,
    const float* __restrict__ sigma, const float* __restrict__ mu,
    const float* __restrict__ x0, float* __restrict__ out)
{
    const int tid = threadIdx.x;
    const int w = tid >> 6, lane = tid & 63;
    const int sl = lane >> 3, um = lane & 7;
    const int bid = blockIdx.x, b = bid >> 3;
    const int ug = (bid & 7) * 32 + w * 8 + um;
    const int d0 = sl * 8;
    __shared__ float sx[2][8 * D];
    float sg[8], cc[8], aa[8];
    {
        const float* sp = sigma + ug * D + d0;
        const float* mp = mu + ug * D + d0;
        const float* ap = A + ug * D + d0;
#pragma unroll
        for (int i = 0; i < 8; ++i) {
            float s_ = sp[i], m_ = mp[i];
            sg[i] = -L2E * s_; cc[i] = L2E * s_ * m_; aa[i] = ap[i];
        }
    }
    float x = x0[ug];
    const float* ib = inp + (size_t)b * TT * D;
    float* ob = out + (size_t)b * TT * U + ug;
    sx[0][tid] = ib[tid]; sx[0][tid + 256] = ib[tid + 256];
    __syncthreads();
    for (int g = 0; g < TT / 8; ++g) {
        float p0 = 0.f, p1 = 0.f;
        if (g < TT / 8 - 1) {
            p0 = ib[(g + 1) * 512 + tid];
            p1 = ib[(g + 1) * 512 + tid + 256];
        }
        const float* sxc = sx[g & 1];
#pragma unroll
        for (int j = 0; j < 8; ++j) {
            const float* xr = sxc + j * D + d0;
            float fs = 0.0f, sA = 0.0f;
#pragma unroll
            for (int i = 0; i < 8; ++i) {
                float e = EXP2(fmaf(sg[i], xr[i], cc[i]));
                float f = RCP(1.0f + e);
                fs += f; sA = fmaf(aa[i], f, sA);
            }
            fs += __shfl_xor(fs, 8);  sA += __shfl_xor(sA, 8);
            fs += __shfl_xor(fs, 16); sA += __shfl_xor(sA, 16);
            fs += __shfl_xor(fs, 32); sA += __shfl_xor(sA, 32);
            float sv = sA * RCP(1.0f + fs);
            float av = EXP2(fmaf(-L2E, fs, -L2E));
            x = fmaf(av, x - sv, sv);
            if (sl == 0) ob[(size_t)(g * 8 + j) * U] = x;
        }
        if (g < TT / 8 - 1) {
            float* sxn = sx[(g + 1) & 1];
            sxn[tid] = p0; sxn[tid + 256] = p1;
        }
        __syncthreads();
    }
}

extern "C" void kernel_launch(void* const* d_in, const int* in_sizes, int n_in,
                              void* d_out, int out_size, void* d_ws, size_t ws_size,
                              hipStream_t stream) {
    const float* inp   = (const float*)d_in[0];
    const float* A     = (const float*)d_in[1];
    const float* sigma = (const float*)d_in[2];
    const float* mu    = (const float*)d_in[3];
    const float* x0    = (const float*)d_in[4];
    float* out = (float*)d_out;

    if (ws_size < WT_BYTES + 4096) {
        ltc_fused2_kernel<<<dim3(BB * 8), dim3(256), 0, stream>>>(inp, A, sigma, mu, x0, out);
        return;
    }

    f16*   Wt   = (f16*)d_ws;
    float* bias = (float*)((char*)d_ws + WT_BYTES);

    wgen<<<dim3(U), dim3(64), 0, stream>>>(A, sigma, mu, Wt, bias);
    gemm_ltc<<<dim3((BT / 128) * 4), dim3(256), 0, stream>>>(inp, Wt, bias, out);
}

// Round 14
// 88.510 us; speedup vs baseline: 1.1443x; 1.1443x over previous
//
#include <hip/hip_runtime.h>

// LTC via Chebyshev-GEMM, v9: v7 + T4 counted-vmcnt pipeline.
//   out[bt,u] = sA/(1+fs); fs,sA = [BT x 448]*[448 x 512] fp16 GEMM.
// R13 diagnosis: v3/v7/v8 all stall because every K-step's __syncthreads
// drains vmcnt(0) -> the B-stage L2 latency serializes into every phase.
// v9: triple-buffer B; phase ks issues STAGEB(ks+2); barrier is raw
//   s_waitcnt vmcnt(4) lgkmcnt(0); s_barrier
// -> only stage ks+1 must land; stage ks+2 stays in flight ACROSS the
// barrier (never drain to 0 in the main loop). A stays in LDS dbuf (v7,
// proven best); lgkmcnt(0) at the barrier publishes the A ds_writes.

typedef _Float16 f16;
typedef _Float16 f16x4 __attribute__((ext_vector_type(4)));
typedef _Float16 f16x8 __attribute__((ext_vector_type(8)));
typedef float f32x4 __attribute__((ext_vector_type(4)));

#if __has_builtin(__builtin_amdgcn_rcpf)
#define RCP(x) __builtin_amdgcn_rcpf(x)
#else
#define RCP(x) (1.0f / (x))
#endif
#if __has_builtin(__builtin_amdgcn_exp2f)
#define EXP2(x) __builtin_amdgcn_exp2f(x)
#else
#define EXP2(x) exp2f(x)
#endif

namespace {
constexpr int D  = 64, U = 256, TT = 1024, BB = 128;
constexpr int BT = BB * TT;              // 131072 GEMM rows
constexpr int NK = 8;                    // degree 7
constexpr int KD = (NK - 1) * 64;        // K = 448
constexpr int ND = 2 * U;                // N = 512
constexpr float SCALE = 6.5f;
constexpr size_t WT_BYTES = (size_t)ND * KD * sizeof(f16);
constexpr float L2E = 1.4426950408889634f;
}

// ---------------- kernel 0: per-(u,d) Chebyshev coefficients ----------------
__global__ __launch_bounds__(64) void wgen(
    const float* __restrict__ Aw, const float* __restrict__ sg,
    const float* __restrict__ mu, f16* __restrict__ Wt, float* __restrict__ bias)
{
    const int u = blockIdx.x, d = threadIdx.x;
    const int id = u * 64 + d;
    const float s = sg[id], m = mu[id], a = Aw[id];
    float g[NK], th[NK];
    float q0 = 0.f;
#pragma unroll
    for (int j = 0; j < NK; ++j) {
        th[j] = 3.14159265358979323846f * (float)(2 * j + 1) / (float)(2 * NK);
        float xj = SCALE * cosf(th[j]);
        g[j] = 1.f / (1.f + expf(-s * (xj - m)));
        q0 += g[j];
    }
    q0 *= (1.f / NK);
#pragma unroll
    for (int k = 1; k < NK; ++k) {
        float qk = 0.f;
#pragma unroll
        for (int j = 0; j < NK; ++j) qk += g[j] * cosf((float)k * th[j]);
        qk *= (2.f / NK);
        Wt[(size_t)(2 * u)     * KD + (k - 1) * 64 + d] = (f16)qk;
        Wt[(size_t)(2 * u + 1) * KD + (k - 1) * 64 + d] = (f16)(a * qk);
    }
    float b0 = q0, b1 = a * q0;
#pragma unroll
    for (int off = 1; off < 64; off <<= 1) {
        b0 += __shfl_xor(b0, off);
        b1 += __shfl_xor(b1, off);
    }
    if (d == 0) { bias[2 * u] = 1.f + b0; bias[2 * u + 1] = b1; }
}

// ---------------- fused GEMM, A-dbuf + B-tribuf, counted vmcnt ----------------
#define GLDS16(g, l) __builtin_amdgcn_global_load_lds( \
    (const __attribute__((address_space(1))) void*)(g), \
    (__attribute__((address_space(3))) void*)(l), 16, 0, 0)

__global__ __launch_bounds__(256) void gemm_ltc(
    const float* __restrict__ Xg, const f16* __restrict__ Wt,
    const float* __restrict__ bias, float* __restrict__ outp)
{
    const int tid = threadIdx.x;
    // XCD swizzle (v3/v7-identical: FETCH 18MB)
    const int cpx  = gridDim.x >> 3;
    const int swz  = (blockIdx.x & 7) * cpx + (blockIdx.x >> 3);
    const int nblk = swz & 3;            // 128 N-cols each
    const int mblk = swz >> 2;           // 128 rows each
    const int lane = tid & 63, w = tid >> 6;
    const int wr = w >> 1, wc = w & 1;   // 2x2 waves, 64x64 each
    const int fr = lane & 15, fq = lane >> 4;

    __shared__ f16 Ash[2][128 * 64];     // 16 KB x2 (A dbuf)
    __shared__ f16 Bsh[3][128 * 64];     // 16 KB x3 (B tri-buf)

    f32x4 acc[4][4];
#pragma unroll
    for (int m = 0; m < 4; ++m)
#pragma unroll
        for (int n = 0; n < 4; ++n) acc[m][n] = f32x4{0.f, 0.f, 0.f, 0.f};

    // ---- x-tile load FIRST (so the convert's vmcnt wait keeps glds in flight)
    const int xr = tid >> 4, xc = tid & 15;
    const float* xb = Xg + (size_t)(mblk * 128 + xr) * 64 + xc * 4;
    f32x4 xv[8];
#pragma unroll
    for (int i = 0; i < 8; ++i)
        xv[i] = *(const f32x4*)(xb + (size_t)i * 16 * 64);

    // ---- B staging (src-col XOR permute, linear glds dest) — v7-identical
    const int srow8 = tid >> 3, slot = tid & 7;
    const int scol  = ((slot ^ (srow8 & 7)) * 8);
    const f16* Bb = Wt + (size_t)(nblk * 128 + srow8) * KD + scol;
#define STAGEB(buf, ks)                                                     \
    {                                                                       \
        _Pragma("unroll")                                                   \
        for (int i = 0; i < 4; ++i)                                         \
            GLDS16(Bb + (size_t)i * 32 * KD + (ks) * 64,                    \
                   &Bsh[buf][i * 2048 + tid * 8]);                          \
    }

    STAGEB(0, 0);
    STAGEB(1, 1);

    // ---- Chebyshev init (consumes xv -> compiler waits for X only)
    f16x4 x2h[8], tp[8], tc[8];
#pragma unroll
    for (int i = 0; i < 8; ++i) {
        const float s = 1.0f / SCALE;
        f16x4 t;
        t[0] = (f16)(xv[i][0] * s); t[1] = (f16)(xv[i][1] * s);
        t[2] = (f16)(xv[i][2] * s); t[3] = (f16)(xv[i][3] * s);
        tc[i]  = t;
        x2h[i] = t + t;
        tp[i]  = f16x4{(f16)1.f, (f16)1.f, (f16)1.f, (f16)1.f};
    }

    // A write addresses (swizzled; v7-identical)
    const int aoff = (((xc >> 1) ^ (xr & 7)) * 16) + (xc & 1) * 8;
#pragma unroll
    for (int i = 0; i < 8; ++i)
        *(f16x4*)((char*)Ash[0] + aoff + (xr + 16 * i) * 128) = tc[i];  // T_1

    // stage0 landed (stage1's 4 stay in flight), A T_1 visible
    asm volatile("s_waitcnt vmcnt(4) lgkmcnt(0)\n\ts_barrier" ::: "memory");

    // ---- MFMA read offsets (v7-identical)
    const int rxr = fr & 7;
    const int arow = (wr * 64 + fr) * 128;
    const int brow = (wc * 64 + fr) * 128;
    int colu[2];
#pragma unroll
    for (int kk = 0; kk < 2; ++kk) colu[kk] = (((kk * 4 + fq) ^ rxr) * 16);

#pragma unroll
    for (int ks = 0; ks < KD / 64; ++ks) {
        const int c = ks & 1;
        if (ks + 2 < KD / 64) STAGEB((ks + 2) % 3, ks + 2);  // 2-deep prefetch
        const char* Ac = (const char*)Ash[c];
        const char* Bc = (const char*)Bsh[ks % 3];
#pragma unroll
        for (int kk = 0; kk < 2; ++kk) {
            f16x8 af[4], bf[4];
#pragma unroll
            for (int m = 0; m < 4; ++m)
                af[m] = *(const f16x8*)(Ac + arow + m * 2048 + colu[kk]);
#pragma unroll
            for (int n = 0; n < 4; ++n)
                bf[n] = *(const f16x8*)(Bc + brow + n * 2048 + colu[kk]);
#pragma unroll
            for (int m = 0; m < 4; ++m)
#pragma unroll
                for (int n = 0; n < 4; ++n)
                    acc[m][n] = __builtin_amdgcn_mfma_f32_16x16x32_f16(
                        af[m], bf[n], acc[m][n], 0, 0, 0);
        }
        if (ks < KD / 64 - 1) {
            // T-advance + write NEXT A-tile into the other buffer (WAR-safe:
            // Ash[c^1] readers finished before the previous barrier)
            char* const an = (char*)Ash[c ^ 1] + aoff;
#pragma unroll
            for (int i = 0; i < 8; ++i) {
                f16x4 tn = x2h[i] * tc[i] - tp[i];
                tp[i] = tc[i]; tc[i] = tn;
                *(f16x4*)(an + (xr + 16 * i) * 128) = tn;
            }
        }
        // counted barrier: wait stage ks+1 only (stage ks+2 stays in flight)
        if (ks <= KD / 64 - 3) {
            asm volatile("s_waitcnt vmcnt(4) lgkmcnt(0)\n\ts_barrier" ::: "memory");
        } else if (ks == KD / 64 - 2) {
            asm volatile("s_waitcnt vmcnt(0) lgkmcnt(0)\n\ts_barrier" ::: "memory");
        }
        // ks == last: no barrier; epilogue follows
    }

    // ---- epilogue (v7-identical): pair (2u,2u+1) via shfl_xor(1)
    const int ncb = nblk * 128 + wc * 64;
    float bia[4];
#pragma unroll
    for (int n = 0; n < 4; ++n) bia[n] = bias[ncb + n * 16 + fr];
    const int growb = mblk * 128 + wr * 64;
    const bool evenl = !(fr & 1);
#pragma unroll
    for (int m = 0; m < 4; ++m) {
        const int r0 = growb + m * 16 + fq * 4;
#pragma unroll
        for (int n = 0; n < 4; ++n) {
            const int ucol = (ncb + n * 16 + fr) >> 1;
            f32x4 v = acc[m][n];
#pragma unroll
            for (int e = 0; e < 4; ++e) {
                float full = v[e] + bia[n];
                float oth  = __shfl_xor(full, 1);
                if (evenl) outp[(size_t)(r0 + e) * U + ucol] = oth * RCP(full);
            }
        }
    }
}

// ---------------- fallback (proven R3 kernel) for tiny ws ----------------
__global__ __launch_bounds__(256) void ltc_fused2_kernel(
    const float* __restrict__ inp, const float* __restrict__ A,
    const float* __restrict__ sigma, const float* __restrict__ mu,
    const float* __restrict__ x0, float* __restrict__ out)
{
    const int tid = threadIdx.x;
    const int w = tid >> 6, lane = tid & 63;
    const int sl = lane >> 3, um = lane & 7;
    const int bid = blockIdx.x, b = bid >> 3;
    const int ug = (bid & 7) * 32 + w * 8 + um;
    const int d0 = sl * 8;
    __shared__ float sx[2][8 * D];
    float sg[8], cc[8], aa[8];
    {
        const float* sp = sigma + ug * D + d0;
        const float* mp = mu + ug * D + d0;
        const float* ap = A + ug * D + d0;
#pragma unroll
        for (int i = 0; i < 8; ++i) {
            float s_ = sp[i], m_ = mp[i];
            sg[i] = -L2E * s_; cc[i] = L2E * s_ * m_; aa[i] = ap[i];
        }
    }
    float x = x0[ug];
    const float* ib = inp + (size_t)b * TT * D;
    float* ob = out + (size_t)b * TT * U + ug;
    sx[0][tid] = ib[tid]; sx[0][tid + 256] = ib[tid + 256];
    __syncthreads();
    for (int g = 0; g < TT / 8; ++g) {
        float p0 = 0.f, p1 = 0.f;
        if (g < TT / 8 - 1) {
            p0 = ib[(g + 1) * 512 + tid];
            p1 = ib[(g + 1) * 512 + tid + 256];
        }
        const float* sxc = sx[g & 1];
#pragma unroll
        for (int j = 0; j < 8; ++j) {
            const float* xr = sxc + j * D + d0;
            float fs = 0.0f, sA = 0.0f;
#pragma unroll
            for (int i = 0; i < 8; ++i) {
                float e = EXP2(fmaf(sg[i], xr[i], cc[i]));
                float f = RCP(1.0f + e);
                fs += f; sA = fmaf(aa[i], f, sA);
            }
            fs += __shfl_xor(fs, 8);  sA += __shfl_xor(sA, 8);
            fs += __shfl_xor(fs, 16); sA += __shfl_xor(sA, 16);
            fs += __shfl_xor(fs, 32); sA += __shfl_xor(sA, 32);
            float sv = sA * RCP(1.0f + fs);
            float av = EXP2(fmaf(-L2E, fs, -L2E));
            x = fmaf(av, x - sv, sv);
            if (sl == 0) ob[(size_t)(g * 8 + j) * U] = x;
        }
        if (g < TT / 8 - 1) {
            float* sxn = sx[(g + 1) & 1];
            sxn[tid] = p0; sxn[tid + 256] = p1;
        }
        __syncthreads();
    }
}

extern "C" void kernel_launch(void* const* d_in, const int* in_sizes, int n_in,
                              void* d_out, int out_size, void* d_ws, size_t ws_size,
                              hipStream_t stream) {
    const float* inp   = (const float*)d_in[0];
    const float* A     = (const float*)d_in[1];
    const float* sigma = (const float*)d_in[2];
    const float* mu    = (const float*)d_in[3];
    const float* x0    = (const float*)d_in[4];
    float* out = (float*)d_out;

    if (ws_size < WT_BYTES + 4096) {
        ltc_fused2_kernel<<<dim3(BB * 8), dim3(256), 0, stream>>>(inp, A, sigma, mu, x0, out);
        return;
    }

    f16*   Wt   = (f16*)d_ws;
    float* bias = (float*)((char*)d_ws + WT_BYTES);

    wgen<<<dim3(U), dim3(64), 0, stream>>>(A, sigma, mu, Wt, bias);
    gemm_ltc<<<dim3((BT / 128) * 4), dim3(256), 0, stream>>>(inp, Wt, bias, out);
}

// Round 15
// 77.070 us; speedup vs baseline: 1.3141x; 1.1484x over previous
//
#include <hip/hip_runtime.h>

// LTC via Chebyshev-GEMM, v10: v7 K-loop + COALESCED epilogue.
// R14 diagnosis: v3/v7/v8/v9 (four different K-loop schedules) all ~103us
// with hbm_gbps ~1.45 TB/s == WRITE(131MB)/dur: the kernel is bound by the
// scattered-32B store pattern of the epilogue (evenl-masked lanes, rows 1KB
// apart), not by the K-loop. v10 routes the output through LDS: all lanes
// ds_write raw (1+fs, sA) pairs into a padded [128][132] f32 tile (aliased
// over the dead A/B staging buffers), then 256 threads stream it out as
// float4 nontemporal stores, 256B contiguous per row. Deletes the shfl_xor
// pairing chain and the divergent masked stores.

typedef _Float16 f16;
typedef _Float16 f16x4 __attribute__((ext_vector_type(4)));
typedef _Float16 f16x8 __attribute__((ext_vector_type(8)));
typedef float f32x4 __attribute__((ext_vector_type(4)));

#if __has_builtin(__builtin_amdgcn_rcpf)
#define RCP(x) __builtin_amdgcn_rcpf(x)
#else
#define RCP(x) (1.0f / (x))
#endif
#if __has_builtin(__builtin_amdgcn_exp2f)
#define EXP2(x) __builtin_amdgcn_exp2f(x)
#else
#define EXP2(x) exp2f(x)
#endif

namespace {
constexpr int D  = 64, U = 256, TT = 1024, BB = 128;
constexpr int BT = BB * TT;              // 131072 GEMM rows
constexpr int NK = 8;                    // degree 7
constexpr int KD = (NK - 1) * 64;        // K = 448
constexpr int ND = 2 * U;                // N = 512
constexpr int OP = 132;                  // padded out-tile row (f32)
constexpr float SCALE = 6.5f;
constexpr size_t WT_BYTES = (size_t)ND * KD * sizeof(f16);
constexpr float L2E = 1.4426950408889634f;
}

// ---------------- kernel 0: per-(u,d) Chebyshev coefficients ----------------
__global__ __launch_bounds__(64) void wgen(
    const float* __restrict__ Aw, const float* __restrict__ sg,
    const float* __restrict__ mu, f16* __restrict__ Wt, float* __restrict__ bias)
{
    const int u = blockIdx.x, d = threadIdx.x;
    const int id = u * 64 + d;
    const float s = sg[id], m = mu[id], a = Aw[id];
    float g[NK], th[NK];
    float q0 = 0.f;
#pragma unroll
    for (int j = 0; j < NK; ++j) {
        th[j] = 3.14159265358979323846f * (float)(2 * j + 1) / (float)(2 * NK);
        float xj = SCALE * cosf(th[j]);
        g[j] = 1.f / (1.f + expf(-s * (xj - m)));
        q0 += g[j];
    }
    q0 *= (1.f / NK);
#pragma unroll
    for (int k = 1; k < NK; ++k) {
        float qk = 0.f;
#pragma unroll
        for (int j = 0; j < NK; ++j) qk += g[j] * cosf((float)k * th[j]);
        qk *= (2.f / NK);
        Wt[(size_t)(2 * u)     * KD + (k - 1) * 64 + d] = (f16)qk;
        Wt[(size_t)(2 * u + 1) * KD + (k - 1) * 64 + d] = (f16)(a * qk);
    }
    float b0 = q0, b1 = a * q0;
#pragma unroll
    for (int off = 1; off < 64; off <<= 1) {
        b0 += __shfl_xor(b0, off);
        b1 += __shfl_xor(b1, off);
    }
    if (d == 0) { bias[2 * u] = 1.f + b0; bias[2 * u + 1] = b1; }  // +1 = OMEGA
}

// ---------------- fused GEMM (v7 K-loop) + coalesced epilogue ----------------
#define GLDS16(g, l) __builtin_amdgcn_global_load_lds( \
    (const __attribute__((address_space(1))) void*)(g), \
    (__attribute__((address_space(3))) void*)(l), 16, 0, 0)

__global__ __launch_bounds__(256) void gemm_ltc(
    const float* __restrict__ Xg, const f16* __restrict__ Wt,
    const float* __restrict__ bias, float* __restrict__ outp)
{
    const int tid = threadIdx.x;
    // XCD swizzle (v3/v7-identical)
    const int cpx  = gridDim.x >> 3;
    const int swz  = (blockIdx.x & 7) * cpx + (blockIdx.x >> 3);
    const int nblk = swz & 3;            // 128 pair-cols each
    const int mblk = swz >> 2;           // 128 rows each
    const int lane = tid & 63, w = tid >> 6;
    const int wr = w >> 1, wc = w & 1;   // 2x2 waves, 64x64 each
    const int fr = lane & 15, fq = lane >> 4;

    // staging buffers and the out-transpose tile alias the same pool
    __shared__ union SM {
        struct { f16 A[2][128 * 64]; f16 B[2][128 * 64]; } st;  // 64 KB
        float o[128 * OP];                                      // 67.6 KB
    } sm;

    f32x4 acc[4][4];
#pragma unroll
    for (int m = 0; m < 4; ++m)
#pragma unroll
        for (int n = 0; n < 4; ++n) acc[m][n] = f32x4{0.f, 0.f, 0.f, 0.f};

    // ---- B staging (src-col XOR permute, linear glds dest) — v7-identical
    const int srow8 = tid >> 3, slot = tid & 7;
    const int scol  = ((slot ^ (srow8 & 7)) * 8);
    const f16* Bb = Wt + (size_t)(nblk * 128 + srow8) * KD + scol;
#define STAGEB(buf, ks)                                                     \
    {                                                                       \
        _Pragma("unroll")                                                   \
        for (int i = 0; i < 4; ++i)                                         \
            GLDS16(Bb + (size_t)i * 32 * KD + (ks) * 64,                    \
                   &sm.st.B[buf][i * 2048 + tid * 8]);                      \
    }

    STAGEB(0, 0);

    // ---- x-tile load + Chebyshev init (v7-identical)
    const int xr = tid >> 4, xc = tid & 15;
    const float* xb = Xg + (size_t)(mblk * 128 + xr) * 64 + xc * 4;
    f32x4 xv[8];
#pragma unroll
    for (int i = 0; i < 8; ++i)
        xv[i] = *(const f32x4*)(xb + (size_t)i * 16 * 64);

    f16x4 x2h[8], tp[8], tc[8];
#pragma unroll
    for (int i = 0; i < 8; ++i) {
        const float s = 1.0f / SCALE;
        f16x4 t;
        t[0] = (f16)(xv[i][0] * s); t[1] = (f16)(xv[i][1] * s);
        t[2] = (f16)(xv[i][2] * s); t[3] = (f16)(xv[i][3] * s);
        tc[i]  = t;
        x2h[i] = t + t;
        tp[i]  = f16x4{(f16)1.f, (f16)1.f, (f16)1.f, (f16)1.f};
    }

    // A write addresses (swizzled; v7-identical)
    const int aoff = (((xc >> 1) ^ (xr & 7)) * 16) + (xc & 1) * 8;
#pragma unroll
    for (int i = 0; i < 8; ++i)
        *(f16x4*)((char*)&sm.st.A[0][0] + aoff + (xr + 16 * i) * 128) = tc[i];

    __syncthreads();   // B0 + T_1 ready

    // ---- MFMA read offsets (v7-identical)
    const int rxr = fr & 7;
    const int arow = (wr * 64 + fr) * 128;
    const int brow = (wc * 64 + fr) * 128;
    int colu[2];
#pragma unroll
    for (int kk = 0; kk < 2; ++kk) colu[kk] = (((kk * 4 + fq) ^ rxr) * 16);

#pragma unroll
    for (int ks = 0; ks < KD / 64; ++ks) {
        const int c = ks & 1;
        if (ks < KD / 64 - 1) STAGEB(c ^ 1, ks + 1);   // issue first
        const char* Ac = (const char*)&sm.st.A[c][0];
        const char* Bc = (const char*)&sm.st.B[c][0];
#pragma unroll
        for (int kk = 0; kk < 2; ++kk) {
            f16x8 af[4], bf[4];
#pragma unroll
            for (int m = 0; m < 4; ++m)
                af[m] = *(const f16x8*)(Ac + arow + m * 2048 + colu[kk]);
#pragma unroll
            for (int n = 0; n < 4; ++n)
                bf[n] = *(const f16x8*)(Bc + brow + n * 2048 + colu[kk]);
#pragma unroll
            for (int m = 0; m < 4; ++m)
#pragma unroll
                for (int n = 0; n < 4; ++n)
                    acc[m][n] = __builtin_amdgcn_mfma_f32_16x16x32_f16(
                        af[m], bf[n], acc[m][n], 0, 0, 0);
        }
        if (ks < KD / 64 - 1) {
            char* const an = (char*)&sm.st.A[c ^ 1][0] + aoff;
#pragma unroll
            for (int i = 0; i < 8; ++i) {
                f16x4 tn = x2h[i] * tc[i] - tp[i];
                tp[i] = tc[i]; tc[i] = tn;
                *(f16x4*)(an + (xr + 16 * i) * 128) = tn;
            }
        }
        __syncthreads();
    }
    // (last barrier of the loop: all waves done reading st.A/st.B -> pool free)

    // ---- epilogue 1: dump raw (1+fs, sA) pairs into padded LDS tile
    float bia[4];
    const int ncb = nblk * 128 + wc * 64;
#pragma unroll
    for (int n = 0; n < 4; ++n) bia[n] = bias[ncb + n * 16 + fr];
#pragma unroll
    for (int m = 0; m < 4; ++m) {
        const int lr = wr * 64 + m * 16 + fq * 4;
#pragma unroll
        for (int n = 0; n < 4; ++n) {
            const int lc = wc * 64 + n * 16 + fr;
            f32x4 v = acc[m][n];
#pragma unroll
            for (int e = 0; e < 4; ++e)
                sm.o[(lr + e) * OP + lc] = v[e] + bia[n];
        }
    }
    __syncthreads();

    // ---- epilogue 2: coalesced float4 stores (256B contiguous per row)
    const size_t orow0 = (size_t)mblk * 128;
    const int    ocol0 = nblk * 64;
#pragma unroll
    for (int pass = 0; pass < 8; ++pass) {
        const int idx = pass * 256 + tid;
        const int r = idx >> 4, o = idx & 15;
        const float* p = &sm.o[r * OP + 8 * o];
        f32x4 a = *(const f32x4*)p;
        f32x4 b = *(const f32x4*)(p + 4);
        f32x4 s;
        s[0] = a[1] * RCP(a[0]);
        s[1] = a[3] * RCP(a[2]);
        s[2] = b[1] * RCP(b[0]);
        s[3] = b[3] * RCP(b[2]);
        __builtin_nontemporal_store(s,
            (f32x4*)&outp[(orow0 + r) * U + ocol0 + 4 * o]);
    }
}

// ---------------- fallback (proven R3 kernel) for tiny ws ----------------
__global__ __launch_bounds__(256) void ltc_fused2_kernel(
    const float* __restrict__ inp, const float* __restrict__ A,
    const float* __restrict__ sigma, const float* __restrict__ mu,
    const float* __restrict__ x0, float* __restrict__ out)
{
    const int tid = threadIdx.x;
    const int w = tid >> 6, lane = tid & 63;
    const int sl = lane >> 3, um = lane & 7;
    const int bid = blockIdx.x, b = bid >> 3;
    const int ug = (bid & 7) * 32 + w * 8 + um;
    const int d0 = sl * 8;
    __shared__ float sx[2][8 * D];
    float sg[8], cc[8], aa[8];
    {
        const float* sp = sigma + ug * D + d0;
        const float* mp = mu + ug * D + d0;
        const float* ap = A + ug * D + d0;
#pragma unroll
        for (int i = 0; i < 8; ++i) {
            float s_ = sp[i], m_ = mp[i];
            sg[i] = -L2E * s_; cc[i] = L2E * s_ * m_; aa[i] = ap[i];
        }
    }
    float x = x0[ug];
    const float* ib = inp + (size_t)b * TT * D;
    float* ob = out + (size_t)b * TT * U + ug;
    sx[0][tid] = ib[tid]; sx[0][tid + 256] = ib[tid + 256];
    __syncthreads();
    for (int g = 0; g < TT / 8; ++g) {
        float p0 = 0.f, p1 = 0.f;
        if (g < TT / 8 - 1) {
            p0 = ib[(g + 1) * 512 + tid];
            p1 = ib[(g + 1) * 512 + tid + 256];
        }
        const float* sxc = sx[g & 1];
#pragma unroll
        for (int j = 0; j < 8; ++j) {
            const float* xr = sxc + j * D + d0;
            float fs = 0.0f, sA = 0.0f;
#pragma unroll
            for (int i = 0; i < 8; ++i) {
                float e = EXP2(fmaf(sg[i], xr[i], cc[i]));
                float f = RCP(1.0f + e);
                fs += f; sA = fmaf(aa[i], f, sA);
            }
            fs += __shfl_xor(fs, 8);  sA += __shfl_xor(sA, 8);
            fs += __shfl_xor(fs, 16); sA += __shfl_xor(sA, 16);
            fs += __shfl_xor(fs, 32); sA += __shfl_xor(sA, 32);
            float sv = sA * RCP(1.0f + fs);
            float av = EXP2(fmaf(-L2E, fs, -L2E));
            x = fmaf(av, x - sv, sv);
            if (sl == 0) ob[(size_t)(g * 8 + j) * U] = x;
        }
        if (g < TT / 8 - 1) {
            float* sxn = sx[(g + 1) & 1];
            sxn[tid] = p0; sxn[tid + 256] = p1;
        }
        __syncthreads();
    }
}

extern "C" void kernel_launch(void* const* d_in, const int* in_sizes, int n_in,
                              void* d_out, int out_size, void* d_ws, size_t ws_size,
                              hipStream_t stream) {
    const float* inp   = (const float*)d_in[0];
    const float* A     = (const float*)d_in[1];
    const float* sigma = (const float*)d_in[2];
    const float* mu    = (const float*)d_in[3];
    const float* x0    = (const float*)d_in[4];
    float* out = (float*)d_out;

    if (ws_size < WT_BYTES + 4096) {
        ltc_fused2_kernel<<<dim3(BB * 8), dim3(256), 0, stream>>>(inp, A, sigma, mu, x0, out);
        return;
    }

    f16*   Wt   = (f16*)d_ws;
    float* bias = (float*)((char*)d_ws + WT_BYTES);

    wgen<<<dim3(U), dim3(64), 0, stream>>>(A, sigma, mu, Wt, bias);
    gemm_ltc<<<dim3((BT / 128) * 4), dim3(256), 0, stream>>>(inp, Wt, bias, out);
}